// Round 2
// baseline (585.460 us; speedup 1.0000x reference)
//
#include <hip/hip_runtime.h>
#include <type_traits>

typedef __bf16 bf16;
typedef __bf16 bf16x8 __attribute__((ext_vector_type(8)));
typedef float f32x4 __attribute__((ext_vector_type(4)));

// ---------------------------------------------------------------------------
// Weight transpose + cast: in [K][N] fp32 -> out [N][K] bf16, 64x64 tiles
// ---------------------------------------------------------------------------
__global__ __launch_bounds__(256) void transpose_f32_bf16(
    const float* __restrict__ in, bf16* __restrict__ out, int K, int N) {
  __shared__ __attribute__((aligned(16))) bf16 tile[64 * 72];
  const int k0 = blockIdx.y * 64, n0 = blockIdx.x * 64;
  const int tid = threadIdx.x;
  for (int c = tid; c < 1024; c += 256) {  // 64 rows x 16 float4-chunks
    int ki = c >> 4, j4 = c & 15;
    float4 f = *reinterpret_cast<const float4*>(in + (size_t)(k0 + ki) * N + n0 + j4 * 4);
    bf16* t = &tile[ki * 72 + j4 * 4];
    t[0] = (bf16)f.x; t[1] = (bf16)f.y; t[2] = (bf16)f.z; t[3] = (bf16)f.w;
  }
  __syncthreads();
  for (int c = tid; c < 512; c += 256) {
    int ni = c >> 3, k8 = c & 7;
    bf16x8 v;
    for (int j = 0; j < 8; j++) v[j] = tile[(k8 * 8 + j) * 72 + ni];
    *reinterpret_cast<bf16x8*>(out + (size_t)(n0 + ni) * K + k0 + k8 * 8) = v;
  }
}

// ---------------------------------------------------------------------------
// GEMM: C[M,N] = A[M,K] * Bt[N,K]^T   (bf16 MFMA, f32 accum)
// AT = float (cast during staging) or bf16; CT = bf16 or float.
// 128x128 tile, BK=64, 4 waves each computing 64x64 (4x4 of 16x16x32 MFMA)
// ---------------------------------------------------------------------------
#define BK 64
#define LDK 72  // +8 bf16 pad: LDS row stride 144 B -> 2-way bank alias (free)

template <typename AT, typename CT>
__global__ __launch_bounds__(256, 2) void gemm_tmpl(
    const AT* __restrict__ A, const bf16* __restrict__ Bt,
    CT* __restrict__ C, int M, int N, int K) {
  __shared__ __attribute__((aligned(16))) bf16 As[128 * LDK];
  __shared__ __attribute__((aligned(16))) bf16 Bs[128 * LDK];
  const int tid = threadIdx.x;
  const int wave = tid >> 6;
  const int lane = tid & 63;
  const int l15 = lane & 15;
  const int quad = lane >> 4;
  const int m0 = blockIdx.y * 128;
  const int n0 = blockIdx.x * 128;
  const int wm = (wave >> 1) * 64;
  const int wn = (wave & 1) * 64;

  f32x4 acc[4][4] = {};

  for (int kt = 0; kt < K; kt += BK) {
    __syncthreads();
    for (int c = tid; c < 128 * BK / 8; c += 256) {
      int row = c >> 3, k8 = c & 7;
      bf16x8 v;
      if constexpr (std::is_same<AT, float>::value) {
        const float* p = A + (size_t)(m0 + row) * K + kt + k8 * 8;
        float4 f0 = *reinterpret_cast<const float4*>(p);
        float4 f1 = *reinterpret_cast<const float4*>(p + 4);
        v[0] = (bf16)f0.x; v[1] = (bf16)f0.y; v[2] = (bf16)f0.z; v[3] = (bf16)f0.w;
        v[4] = (bf16)f1.x; v[5] = (bf16)f1.y; v[6] = (bf16)f1.z; v[7] = (bf16)f1.w;
      } else {
        v = *reinterpret_cast<const bf16x8*>(A + (size_t)(m0 + row) * K + kt + k8 * 8);
      }
      *reinterpret_cast<bf16x8*>(&As[row * LDK + k8 * 8]) = v;
    }
    for (int c = tid; c < 128 * BK / 8; c += 256) {
      int row = c >> 3, k8 = c & 7;
      bf16x8 v = *reinterpret_cast<const bf16x8*>(Bt + (size_t)(n0 + row) * K + kt + k8 * 8);
      *reinterpret_cast<bf16x8*>(&Bs[row * LDK + k8 * 8]) = v;
    }
    __syncthreads();
    for (int kk = 0; kk < BK; kk += 32) {
      bf16x8 af[4], bfr[4];
      for (int i = 0; i < 4; i++)
        af[i] = *reinterpret_cast<const bf16x8*>(&As[(wm + i * 16 + l15) * LDK + kk + quad * 8]);
      for (int j = 0; j < 4; j++)
        bfr[j] = *reinterpret_cast<const bf16x8*>(&Bs[(wn + j * 16 + l15) * LDK + kk + quad * 8]);
      for (int i = 0; i < 4; i++)
        for (int j = 0; j < 4; j++)
          acc[i][j] = __builtin_amdgcn_mfma_f32_16x16x32_bf16(af[i], bfr[j], acc[i][j], 0, 0, 0);
    }
  }

  for (int i = 0; i < 4; i++)
    for (int j = 0; j < 4; j++)
      for (int r = 0; r < 4; r++) {
        int row = m0 + wm + i * 16 + quad * 4 + r;
        int col = n0 + wn + j * 16 + l15;
        C[(size_t)row * N + col] = (CT)acc[i][j][r];
      }
}

// ---------------------------------------------------------------------------
// Flash attention (no 1/sqrt(hd) scaling, matching reference).
// qkv: [B*T, 3*1024] bf16 where col = s*1024 + h*64 + d (s in {q,k,v}).
// out: [B*T, 1024] bf16 (attn output, pre-projection).
// Grid: (B*H=64, T/64=32). Block 256 = 4 waves; each wave owns 16 q-rows.
// ---------------------------------------------------------------------------
__global__ __launch_bounds__(256, 2) void attn_kernel(
    const bf16* __restrict__ qkv, bf16* __restrict__ out) {
  __shared__ __attribute__((aligned(16))) bf16 Ks[64 * 72];     // [key][d]
  __shared__ __attribute__((aligned(16))) bf16 Vs[64 * 72];     // [d][key]
  __shared__ __attribute__((aligned(16))) bf16 Ps[4][16 * 72];  // per-wave P

  const int tid = threadIdx.x;
  const int wave = tid >> 6;
  const int lane = tid & 63;
  const int l15 = lane & 15;
  const int quad = lane >> 4;
  const int b = blockIdx.x >> 4;
  const int h = blockIdx.x & 15;
  const int qt0 = blockIdx.y * 64;
  const bf16* base = qkv + (size_t)b * 2048 * 3072 + h * 64;

  // Q fragments for this wave's 16 rows (held in regs across whole loop)
  bf16x8 aq0, aq1;
  {
    const bf16* qrow = base + (size_t)(qt0 + wave * 16 + l15) * 3072;
    aq0 = *reinterpret_cast<const bf16x8*>(qrow + quad * 8);
    aq1 = *reinterpret_cast<const bf16x8*>(qrow + 32 + quad * 8);
  }

  float m_r[4], l_r[4];
  f32x4 o[4] = {};
  for (int r = 0; r < 4; r++) { m_r[r] = -1e30f; l_r[r] = 0.f; }
  const float L2E = 1.44269504f;

  for (int kt = 0; kt < 2048; kt += 64) {
    __syncthreads();
    // stage K row-major, V transposed
    for (int c = tid; c < 512; c += 256) {
      int key = c >> 3, k8 = c & 7;
      const bf16* krow = base + (size_t)(kt + key) * 3072 + 1024;
      bf16x8 kv = *reinterpret_cast<const bf16x8*>(krow + k8 * 8);
      *reinterpret_cast<bf16x8*>(&Ks[key * 72 + k8 * 8]) = kv;
      const bf16* vrow = base + (size_t)(kt + key) * 3072 + 2048;
      bf16x8 vv = *reinterpret_cast<const bf16x8*>(vrow + k8 * 8);
      for (int j = 0; j < 8; j++) Vs[(k8 * 8 + j) * 72 + key] = vv[j];
    }
    __syncthreads();

    // S = Q K^T  (16 q-rows x 64 keys per wave)
    f32x4 s[4];
    for (int n = 0; n < 4; n++) {
      bf16x8 bk0 = *reinterpret_cast<const bf16x8*>(&Ks[(n * 16 + l15) * 72 + quad * 8]);
      bf16x8 bk1 = *reinterpret_cast<const bf16x8*>(&Ks[(n * 16 + l15) * 72 + 32 + quad * 8]);
      f32x4 z = {};
      z = __builtin_amdgcn_mfma_f32_16x16x32_bf16(aq0, bk0, z, 0, 0, 0);
      z = __builtin_amdgcn_mfma_f32_16x16x32_bf16(aq1, bk1, z, 0, 0, 0);
      s[n] = z;
    }

    // online softmax; row r lives in the 16 lanes sharing this quad
    for (int r = 0; r < 4; r++) {
      float v0 = fmaxf(fmaxf(s[0][r], s[1][r]), fmaxf(s[2][r], s[3][r]));
      for (int m = 1; m <= 8; m <<= 1) v0 = fmaxf(v0, __shfl_xor(v0, m, 64));
      float mn = fmaxf(m_r[r], v0);
      float alpha = __builtin_amdgcn_exp2f((m_r[r] - mn) * L2E);
      float p[4], psum = 0.f;
      for (int n = 0; n < 4; n++) {
        p[n] = __builtin_amdgcn_exp2f((s[n][r] - mn) * L2E);
        psum += p[n];
      }
      for (int m = 1; m <= 8; m <<= 1) psum += __shfl_xor(psum, m, 64);
      l_r[r] = l_r[r] * alpha + psum;
      m_r[r] = mn;
      for (int n = 0; n < 4; n++) {
        o[n][r] *= alpha;
        Ps[wave][(quad * 4 + r) * 72 + n * 16 + l15] = (bf16)p[n];
      }
    }

    // O += P V   (P: C-layout -> A-layout via wave-private LDS, no barrier)
    bf16x8 ap0 = *reinterpret_cast<const bf16x8*>(&Ps[wave][l15 * 72 + quad * 8]);
    bf16x8 ap1 = *reinterpret_cast<const bf16x8*>(&Ps[wave][l15 * 72 + 32 + quad * 8]);
    for (int n = 0; n < 4; n++) {
      bf16x8 bv0 = *reinterpret_cast<const bf16x8*>(&Vs[(n * 16 + l15) * 72 + quad * 8]);
      bf16x8 bv1 = *reinterpret_cast<const bf16x8*>(&Vs[(n * 16 + l15) * 72 + 32 + quad * 8]);
      o[n] = __builtin_amdgcn_mfma_f32_16x16x32_bf16(ap0, bv0, o[n], 0, 0, 0);
      o[n] = __builtin_amdgcn_mfma_f32_16x16x32_bf16(ap1, bv1, o[n], 0, 0, 0);
    }
  }

  for (int r = 0; r < 4; r++) {
    float inv = 1.0f / l_r[r];
    int q = qt0 + wave * 16 + quad * 4 + r;
    bf16* orow = out + (size_t)(b * 2048 + q) * 1024 + h * 64;
    for (int n = 0; n < 4; n++) orow[n * 16 + l15] = (bf16)(o[n][r] * inv);
  }
}

// ---------------------------------------------------------------------------
// Launch: transpose weights -> QKV GEMM -> attention -> proj GEMM
// ---------------------------------------------------------------------------
extern "C" void kernel_launch(void* const* d_in, const int* in_sizes, int n_in,
                              void* d_out, int out_size, void* d_ws, size_t ws_size,
                              hipStream_t stream) {
  const float* x = (const float*)d_in[0];       // [8192, 1024] fp32
  const float* w_qkv = (const float*)d_in[1];   // [1024, 3072] fp32
  const float* w_proj = (const float*)d_in[2];  // [1024, 1024] fp32
  float* out = (float*)d_out;                   // [8192, 1024] fp32

  bf16* ws = (bf16*)d_ws;
  bf16* wqkvT = ws;                            // [3072, 1024] bf16
  bf16* wprojT = wqkvT + 3072 * 1024;          // [1024, 1024] bf16
  bf16* qkv = wprojT + 1024 * 1024;            // [8192, 3072] bf16
  bf16* attn_out = qkv + (size_t)8192 * 3072;  // [8192, 1024] bf16

  transpose_f32_bf16<<<dim3(48, 16), 256, 0, stream>>>(w_qkv, wqkvT, 1024, 3072);
  transpose_f32_bf16<<<dim3(16, 16), 256, 0, stream>>>(w_proj, wprojT, 1024, 1024);
  gemm_tmpl<float, bf16><<<dim3(24, 64), 256, 0, stream>>>(x, wqkvT, qkv, 8192, 3072, 1024);
  attn_kernel<<<dim3(64, 32), 256, 0, stream>>>(qkv, attn_out);
  gemm_tmpl<bf16, float><<<dim3(8, 64), 256, 0, stream>>>(attn_out, wprojT, out, 8192, 1024, 1024);
}

// Round 3
// 377.024 us; speedup vs baseline: 1.5528x; 1.5528x over previous
//
#include <hip/hip_runtime.h>

typedef __bf16 bf16;
typedef __bf16 bf16x8 __attribute__((ext_vector_type(8)));
typedef float f32x4 __attribute__((ext_vector_type(4)));
typedef unsigned int uint;
typedef unsigned short ushort;

typedef const __attribute__((address_space(1))) void* gas_ptr;
typedef __attribute__((address_space(3))) void* las_ptr;

__device__ __forceinline__ void load16_lds(const void* g, void* l) {
  __builtin_amdgcn_global_load_lds((gas_ptr)g, (las_ptr)l, 16, 0, 0);
}

// ---------------------------------------------------------------------------
// x fp32 -> bf16 cast (8 elems/thread)
// ---------------------------------------------------------------------------
__global__ __launch_bounds__(256) void cast_f32_bf16(
    const float* __restrict__ in, bf16* __restrict__ out) {
  size_t i = (size_t)blockIdx.x * 256 + threadIdx.x;
  const float4* p = reinterpret_cast<const float4*>(in) + i * 2;
  float4 a = p[0], b = p[1];
  bf16x8 v;
  v[0] = (bf16)a.x; v[1] = (bf16)a.y; v[2] = (bf16)a.z; v[3] = (bf16)a.w;
  v[4] = (bf16)b.x; v[5] = (bf16)b.y; v[6] = (bf16)b.z; v[7] = (bf16)b.w;
  reinterpret_cast<bf16x8*>(out)[i] = v;
}

// ---------------------------------------------------------------------------
// Weight transpose + cast: in [K][N] fp32 -> out [N][K] bf16, 64x64 tiles
// ---------------------------------------------------------------------------
__global__ __launch_bounds__(256) void transpose_f32_bf16(
    const float* __restrict__ in, bf16* __restrict__ out, int K, int N) {
  __shared__ __attribute__((aligned(16))) bf16 tile[64 * 72];
  const int k0 = blockIdx.y * 64, n0 = blockIdx.x * 64;
  const int tid = threadIdx.x;
  for (int c = tid; c < 1024; c += 256) {
    int ki = c >> 4, j4 = c & 15;
    float4 f = *reinterpret_cast<const float4*>(in + (size_t)(k0 + ki) * N + n0 + j4 * 4);
    bf16* t = &tile[ki * 72 + j4 * 4];
    t[0] = (bf16)f.x; t[1] = (bf16)f.y; t[2] = (bf16)f.z; t[3] = (bf16)f.w;
  }
  __syncthreads();
  for (int c = tid; c < 512; c += 256) {
    int ni = c >> 3, k8 = c & 7;
    bf16x8 v;
    for (int j = 0; j < 8; j++) v[j] = tile[(k8 * 8 + j) * 72 + ni];
    *reinterpret_cast<bf16x8*>(out + (size_t)(n0 + ni) * K + k0 + k8 * 8) = v;
  }
}

// ---------------------------------------------------------------------------
// GEMM: C[M,N] = A[M,K] * Bt[N,K]^T  (bf16 in, f32 accum, CT out)
// 128x128 tile, BK=64. Staging via global_load_lds width=16.
// LDS chunk layout: 16B chunk p holds logical (row=p>>3, kc=(p&7)^(row&7)).
// Fragment read for (row,kc): chunk row*8 + (kc^(row&7)) -> bank-even b128s.
// ---------------------------------------------------------------------------
template <typename CT>
__global__ __launch_bounds__(256, 2) void gemm_lds(
    const bf16* __restrict__ A, const bf16* __restrict__ Bt,
    CT* __restrict__ C, int M, int N, int K) {
  __shared__ __attribute__((aligned(16))) bf16 As[128 * 64];
  __shared__ __attribute__((aligned(16))) bf16 Bs[128 * 64];
  const int tid = threadIdx.x;
  const int wave = tid >> 6;
  const int lane = tid & 63;
  const int l15 = lane & 15;
  const int quad = lane >> 4;
  const int m0 = blockIdx.y * 128;
  const int n0 = blockIdx.x * 128;
  const int wm = (wave >> 1) * 64;
  const int wn = (wave & 1) * 64;

  f32x4 acc[4][4] = {};

  for (int kt = 0; kt < K; kt += 64) {
    __syncthreads();
    for (int it = 0; it < 4; ++it) {
      int p = it * 256 + wave * 64 + lane;
      int row = p >> 3, kc = (p & 7) ^ (row & 7);
      load16_lds(A + (size_t)(m0 + row) * K + kt + kc * 8, &As[p * 8]);
      load16_lds(Bt + (size_t)(n0 + row) * K + kt + kc * 8, &Bs[p * 8]);
    }
    __syncthreads();
    for (int kk = 0; kk < 64; kk += 32) {
      const int kc = (kk >> 3) + quad;
      bf16x8 af[4], bfr[4];
      for (int i = 0; i < 4; i++) {
        int row = wm + i * 16 + l15;
        af[i] = *reinterpret_cast<const bf16x8*>(&As[(row * 8 + (kc ^ (row & 7))) * 8]);
      }
      for (int j = 0; j < 4; j++) {
        int row = wn + j * 16 + l15;
        bfr[j] = *reinterpret_cast<const bf16x8*>(&Bs[(row * 8 + (kc ^ (row & 7))) * 8]);
      }
      for (int i = 0; i < 4; i++)
        for (int j = 0; j < 4; j++)
          acc[i][j] = __builtin_amdgcn_mfma_f32_16x16x32_bf16(af[i], bfr[j], acc[i][j], 0, 0, 0);
    }
  }

  for (int i = 0; i < 4; i++)
    for (int j = 0; j < 4; j++)
      for (int r = 0; r < 4; r++) {
        int row = m0 + wm + i * 16 + quad * 4 + r;
        int col = n0 + wn + j * 16 + l15;
        C[(size_t)row * N + col] = (CT)acc[i][j][r];
      }
}

// ---------------------------------------------------------------------------
// Flash attention. qkv: [B*T, 3072] bf16, col = s*1024 + h*64 + d.
// Grid (B*H=64, T/64=32); 4 waves x 16 q-rows.
// Q pre-scaled by log2(e); row-sum via ones-column MFMA.
// Vs: [d][key] as dwords (key pairs), XOR-swizzled; Ps: fp32, stride 68.
// ---------------------------------------------------------------------------
__device__ __forceinline__ int vs_dw(int d, int kdw) {
  return d * 32 + (kdw ^ ((((d >> 3) ^ d) & 7) * 4));
}

__global__ __launch_bounds__(256, 2) void attn_kernel(
    const bf16* __restrict__ qkv, bf16* __restrict__ out) {
  __shared__ __attribute__((aligned(16))) bf16 Ks[64 * 72];   // [key][d], pad 72
  __shared__ __attribute__((aligned(16))) uint Vs[64 * 32];   // swizzled [d][keypair]
  __shared__ __attribute__((aligned(16))) float Ps[4][16 * 68];

  const int tid = threadIdx.x;
  const int wave = tid >> 6;
  const int lane = tid & 63;
  const int l15 = lane & 15;
  const int quad = lane >> 4;
  const int b = blockIdx.x >> 4;
  const int h = blockIdx.x & 15;
  const int qt0 = blockIdx.y * 64;
  const bf16* base = qkv + (size_t)b * 2048 * 3072 + h * 64;
  float* Pw = &Ps[wave][0];
  const float L2E = 1.44269504f;

  // Q fragments, pre-scaled by log2(e)
  bf16x8 aq0, aq1;
  {
    const bf16* qrow = base + (size_t)(qt0 + wave * 16 + l15) * 3072;
    aq0 = *reinterpret_cast<const bf16x8*>(qrow + quad * 8);
    aq1 = *reinterpret_cast<const bf16x8*>(qrow + 32 + quad * 8);
    for (int j = 0; j < 8; j++) {
      aq0[j] = (bf16)((float)aq0[j] * L2E);
      aq1[j] = (bf16)((float)aq1[j] * L2E);
    }
  }

  // ones-column B fragment: B[k][0] = 1 -> lanes with l15==0 hold 1s
  bf16x8 bones = {};
  if (l15 == 0)
    for (int j = 0; j < 8; j++) bones[j] = (bf16)1.0f;

  float m_r[4];
  f32x4 o[4] = {};
  f32x4 l_acc = {};
  for (int r = 0; r < 4; r++) m_r[r] = -1e30f;

  const int kp = tid >> 3;   // key pair 0..31
  const int oct = tid & 7;   // d octet 0..7

  for (int kt = 0; kt < 2048; kt += 64) {
    __syncthreads();
    // K: row-major staging (bank-even b128 writes)
    for (int c = tid; c < 512; c += 256) {
      int key = c >> 3, k8 = c & 7;
      bf16x8 kv = *reinterpret_cast<const bf16x8*>(
          base + (size_t)(kt + key) * 3072 + 1024 + k8 * 8);
      *reinterpret_cast<bf16x8*>(&Ks[key * 72 + k8 * 8]) = kv;
    }
    // V: transposed via dword-pair packing into swizzled layout
    {
      const bf16* v0p = base + (size_t)(kt + 2 * kp) * 3072 + 2048 + oct * 8;
      bf16x8 r0 = *reinterpret_cast<const bf16x8*>(v0p);
      bf16x8 r1 = *reinterpret_cast<const bf16x8*>(v0p + 3072);
      const ushort* u0 = reinterpret_cast<const ushort*>(&r0);
      const ushort* u1 = reinterpret_cast<const ushort*>(&r1);
      for (int i = 0; i < 8; i++)
        Vs[vs_dw(oct * 8 + i, kp)] = (uint)u0[i] | ((uint)u1[i] << 16);
    }
    __syncthreads();

    // S' = (Q*log2e) K^T
    f32x4 s[4];
    for (int n = 0; n < 4; n++) {
      bf16x8 bk0 = *reinterpret_cast<const bf16x8*>(&Ks[(n * 16 + l15) * 72 + quad * 8]);
      bf16x8 bk1 = *reinterpret_cast<const bf16x8*>(&Ks[(n * 16 + l15) * 72 + 32 + quad * 8]);
      f32x4 z = {};
      z = __builtin_amdgcn_mfma_f32_16x16x32_bf16(aq0, bk0, z, 0, 0, 0);
      z = __builtin_amdgcn_mfma_f32_16x16x32_bf16(aq1, bk1, z, 0, 0, 0);
      s[n] = z;
    }

    // online softmax (log2 domain); P -> fp32 LDS (conflict-free stores)
    for (int r = 0; r < 4; r++) {
      float v0 = fmaxf(fmaxf(s[0][r], s[1][r]), fmaxf(s[2][r], s[3][r]));
      for (int m = 1; m <= 8; m <<= 1) v0 = fmaxf(v0, __shfl_xor(v0, m, 64));
      float mn = fmaxf(m_r[r], v0);
      float alpha = __builtin_amdgcn_exp2f(m_r[r] - mn);
      m_r[r] = mn;
      l_acc[r] *= alpha;
      for (int n = 0; n < 4; n++) {
        float p = __builtin_amdgcn_exp2f(s[n][r] - mn);
        o[n][r] *= alpha;
        Pw[(quad * 4 + r) * 68 + n * 16 + l15] = p;
      }
    }

    // P fragments (fp32 LDS -> bf16), wave-synchronous
    bf16x8 ap0, ap1;
    {
      float4 f0 = *reinterpret_cast<const float4*>(&Pw[l15 * 68 + quad * 8]);
      float4 f1 = *reinterpret_cast<const float4*>(&Pw[l15 * 68 + quad * 8 + 4]);
      float4 g0 = *reinterpret_cast<const float4*>(&Pw[l15 * 68 + 32 + quad * 8]);
      float4 g1 = *reinterpret_cast<const float4*>(&Pw[l15 * 68 + 32 + quad * 8 + 4]);
      ap0[0] = (bf16)f0.x; ap0[1] = (bf16)f0.y; ap0[2] = (bf16)f0.z; ap0[3] = (bf16)f0.w;
      ap0[4] = (bf16)f1.x; ap0[5] = (bf16)f1.y; ap0[6] = (bf16)f1.z; ap0[7] = (bf16)f1.w;
      ap1[0] = (bf16)g0.x; ap1[1] = (bf16)g0.y; ap1[2] = (bf16)g0.z; ap1[3] = (bf16)g0.w;
      ap1[4] = (bf16)g1.x; ap1[5] = (bf16)g1.y; ap1[6] = (bf16)g1.z; ap1[7] = (bf16)g1.w;
    }

    // row-sum via ones-column
    l_acc = __builtin_amdgcn_mfma_f32_16x16x32_bf16(ap0, bones, l_acc, 0, 0, 0);
    l_acc = __builtin_amdgcn_mfma_f32_16x16x32_bf16(ap1, bones, l_acc, 0, 0, 0);

    // O += P V  (V fragments from swizzled Vs)
    for (int n = 0; n < 4; n++) {
      int d = n * 16 + l15;
      uint4 u0 = *reinterpret_cast<const uint4*>(&Vs[vs_dw(d, quad * 4)]);
      uint4 u1 = *reinterpret_cast<const uint4*>(&Vs[vs_dw(d, 16 + quad * 4)]);
      bf16x8 bv0 = *reinterpret_cast<const bf16x8*>(&u0);
      bf16x8 bv1 = *reinterpret_cast<const bf16x8*>(&u1);
      o[n] = __builtin_amdgcn_mfma_f32_16x16x32_bf16(ap0, bv0, o[n], 0, 0, 0);
      o[n] = __builtin_amdgcn_mfma_f32_16x16x32_bf16(ap1, bv1, o[n], 0, 0, 0);
    }
  }

  for (int r = 0; r < 4; r++) {
    float lv = __shfl(l_acc[r], quad * 16, 64);
    float inv = 1.0f / lv;
    int q = qt0 + wave * 16 + quad * 4 + r;
    bf16* orow = out + (size_t)(b * 2048 + q) * 1024 + h * 64;
    for (int n = 0; n < 4; n++) orow[n * 16 + l15] = (bf16)(o[n][r] * inv);
  }
}

// ---------------------------------------------------------------------------
// Launch
// ---------------------------------------------------------------------------
extern "C" void kernel_launch(void* const* d_in, const int* in_sizes, int n_in,
                              void* d_out, int out_size, void* d_ws, size_t ws_size,
                              hipStream_t stream) {
  const float* x = (const float*)d_in[0];       // [8192, 1024] fp32
  const float* w_qkv = (const float*)d_in[1];   // [1024, 3072] fp32
  const float* w_proj = (const float*)d_in[2];  // [1024, 1024] fp32
  float* out = (float*)d_out;                   // [8192, 1024] fp32

  bf16* ws = (bf16*)d_ws;
  bf16* x_bf = ws;                                   // [8192,1024]
  bf16* wqkvT = x_bf + (size_t)8192 * 1024;          // [3072,1024]
  bf16* wprojT = wqkvT + 3072 * 1024;                // [1024,1024]
  bf16* qkv = wprojT + 1024 * 1024;                  // [8192,3072]
  bf16* attn_out = qkv + (size_t)8192 * 3072;        // [8192,1024]

  cast_f32_bf16<<<4096, 256, 0, stream>>>(x, x_bf);
  transpose_f32_bf16<<<dim3(48, 16), 256, 0, stream>>>(w_qkv, wqkvT, 1024, 3072);
  transpose_f32_bf16<<<dim3(16, 16), 256, 0, stream>>>(w_proj, wprojT, 1024, 1024);
  gemm_lds<bf16><<<dim3(24, 64), 256, 0, stream>>>(x_bf, wqkvT, qkv, 8192, 3072, 1024);
  attn_kernel<<<dim3(64, 32), 256, 0, stream>>>(qkv, attn_out);
  gemm_lds<float><<<dim3(8, 64), 256, 0, stream>>>(attn_out, wprojT, out, 8192, 1024, 1024);
}